// Round 5
// baseline (209.676 us; speedup 1.0000x reference)
//
#include <hip/hip_runtime.h>

// LocalMean: 5x5 box filter, reflect padding, (32,3,512,512) fp32.
// R4: same straight-line structure as R3, but fix the REAL bottleneck seen in
// counters: VGPR=28 -> compiler serialized all 15 loads (~900cy each, serial).
// (1) __launch_bounds__(256,1) frees the register budget,
// (2) keep-alive asm wall forces all 15 loads in flight before first use,
// (3) XCD-chunked swizzle keeps vertical neighbors in one XCD's L2.

constexpr int H  = 512;
constexpr int W  = 512;
constexpr int QX = W / 4;   // 128 quads per row

__global__ __launch_bounds__(256, 1) void localmean_kernel(const float* __restrict__ in,
                                                           float* __restrict__ out) {
    const int t   = threadIdx.x;
    const int q   = t & (QX - 1);               // x-quad 0..127

    // XCD-chunked swizzle: 24576 blocks, 8 XCDs -> 3072 contiguous wgs each.
    const int bid = (int)blockIdx.x;
    const int wg  = (bid & 7) * (24576 >> 3) + (bid >> 3);
    const int rp    = wg & (H / 2 - 1);         // row-pair 0..255
    const int plane = wg >> 8;                  // 0..95
    const int y     = rp * 2 + (t >> 7);        // output row

    const float* pin = in + (size_t)plane * H * W;

    // ---- load phase: 15 independent loads.
    float4 cu[5];
    float2 lf[5], rt[5];
    const int xl = (q > 0)      ? 4 * q - 2 : 0;
    const int xr = (q < QX - 1) ? 4 * q + 4 : 4 * q - 4;
    #pragma unroll
    for (int k = 0; k < 5; ++k) {
        int gy = y - 2 + k;                     // reflect in y
        gy = (gy < 0) ? -gy : gy;
        gy = (gy >= H) ? (2 * H - 2 - gy) : gy;
        const float* row = pin + (size_t)gy * W;
        cu[k] = *(const float4*)(row + 4 * q);
        lf[k] = *(const float2*)(row + xl);
        rt[k] = *(const float2*)(row + xr);
    }
    // Keep-alive wall: all 40 values live simultaneously -> loads can't be
    // sunk into the compute; one batched issue + single waitcnt.
    #pragma unroll
    for (int k = 0; k < 5; ++k) {
        asm volatile("" :: "v"(cu[k].x), "v"(cu[k].y), "v"(cu[k].z), "v"(cu[k].w),
                           "v"(lf[k].x), "v"(lf[k].y), "v"(rt[k].x), "v"(rt[k].y));
    }

    // ---- compute: per-row 5-tap horizontal sums, accumulate vertically.
    float4 acc = make_float4(0.f, 0.f, 0.f, 0.f);
    #pragma unroll
    for (int k = 0; k < 5; ++k) {
        float2 l = lf[k], r = rt[k];
        if (q == 0)      { l.x = cu[k].z; l.y = cu[k].y; }  // reflect e[-2],e[-1]
        if (q == QX - 1) { r.x = cu[k].z; r.y = cu[k].y; }  // reflect e[512],e[513]
        float s = cu[k].x + cu[k].y + cu[k].z + cu[k].w;
        acc.x += (s - cu[k].w) + l.x + l.y;   // x-2..x+2
        acc.y += s + l.y;                     // x-1..x+3
        acc.z += s + r.x;                     // x  ..x+4
        acc.w += (s - cu[k].x) + r.x + r.y;   // x+1..x+5
    }
    const float inv = 1.0f / 25.0f;
    acc.x *= inv; acc.y *= inv; acc.z *= inv; acc.w *= inv;

    ((float4*)(out + (size_t)plane * H * W + (size_t)y * W))[q] = acc;
}

extern "C" void kernel_launch(void* const* d_in, const int* in_sizes, int n_in,
                              void* d_out, int out_size, void* d_ws, size_t ws_size,
                              hipStream_t stream) {
    const float* in = (const float*)d_in[0];
    float* out = (float*)d_out;
    const int planes = in_sizes[0] / (H * W);   // 96
    dim3 grid(planes * (H / 2));                // 24576 blocks
    dim3 block(256);
    localmean_kernel<<<grid, block, 0, stream>>>(in, out);
}

// Round 6
// 179.975 us; speedup vs baseline: 1.1650x; 1.1650x over previous
//
#include <hip/hip_runtime.h>

// LocalMean 5x5 box filter, reflect pad, (32,3,512,512) fp32.
// R5: bytes-in-flight fix. R1-R4 all plateaued at 1.6-2.9 TB/s because
// regalloc (VGPR 28-32) serialized loads -> ~2.5KB in flight/CU = 4 B/cy.
// global_load_lds needs NO dest VGPRs: issue all 20 tile-loads per wave up
// front (20KB in flight/wave, 160KB/CU), counted vmcnt + raw barriers
// (m201/m218 pattern -- __syncthreads would drain vmcnt(0) and kill it).

constexpr int H = 512;
constexpr int W = 512;
constexpr int ROWS  = 16;   // output rows per chunk
constexpr int LROWS = 20;   // staged rows per chunk (2-row halo each side)
constexpr int QX = W / 4;   // 128 quads per row

#define GLOAD16(gp, lp)                                                        \
    __builtin_amdgcn_global_load_lds(                                          \
        (const __attribute__((address_space(1))) void*)(gp),                   \
        (__attribute__((address_space(3))) void*)(lp), 16, 0, 0)

// Issue 10 global_load_lds (16B) per thread for one 20x512 tile. Wave-uniform
// LDS base + lane*16 (linear layout), per-lane global addr, all coalesced.
__device__ __forceinline__ void stage(const float* __restrict__ pin,
                                      float* ldsbuf, int y0, int t) {
    #pragma unroll
    for (int i = 0; i < 10; ++i) {
        int idx = i * 256 + t;          // quad index in tile (lane-contiguous)
        int r   = idx >> 7;             // staged row 0..19 (wave-uniform)
        int q   = idx & 127;
        int gy  = y0 - 2 + r;           // reflect in y
        gy = (gy < 0) ? -gy : gy;
        gy = (gy >= H) ? (2 * H - 2 - gy) : gy;
        GLOAD16(pin + (size_t)gy * W + q * 4, ldsbuf + (size_t)idx * 4);
    }
}

// 5-tap horizontal sums for quad q of one LDS row.
__device__ __forceinline__ float4 hsum_row(const float* row, int q) {
    float4 cur = *(const float4*)(row + q * 4);
    float2 lf, rt;
    if (q > 0)      lf = *(const float2*)(row + q * 4 - 2);
    else            { lf.x = cur.z; lf.y = cur.y; }      // reflect e[-2]=e[2], e[-1]=e[1]
    if (q < QX - 1) rt = *(const float2*)(row + q * 4 + 4);
    else            { rt.x = cur.z; rt.y = cur.y; }      // reflect e[512]=e[510], e[513]=e[509]
    float s = cur.x + cur.y + cur.z + cur.w;
    float4 h;
    h.x = (s - cur.w) + lf.x + lf.y;
    h.y = s + lf.y;
    h.z = s + rt.x;
    h.w = (s - cur.x) + rt.x + rt.y;
    return h;
}

// Rolling 5-row vertical sum over one staged tile (verified in R2).
__device__ __forceinline__ void compute_tile(const float* buf, float* __restrict__ pout,
                                             int y0, int t) {
    const int tx = t & 127;
    const int ty = t >> 7;                       // 0..1, owns 8 output rows
    const float* base = buf + ty * 8 * W;

    float4 h0 = hsum_row(base + 0 * W, tx);
    float4 h1 = hsum_row(base + 1 * W, tx);
    float4 h2 = hsum_row(base + 2 * W, tx);
    float4 h3 = hsum_row(base + 3 * W, tx);

    const float inv = 1.0f / 25.0f;
    #pragma unroll
    for (int j = 0; j < 8; ++j) {
        float4 h4 = hsum_row(base + (j + 4) * W, tx);
        float4 v;
        v.x = (h0.x + h1.x + h2.x + h3.x + h4.x) * inv;
        v.y = (h0.y + h1.y + h2.y + h3.y + h4.y) * inv;
        v.z = (h0.z + h1.z + h2.z + h3.z + h4.z) * inv;
        v.w = (h0.w + h1.w + h2.w + h3.w + h4.w) * inv;
        ((float4*)(pout + (size_t)(y0 + ty * 8 + j) * W))[tx] = v;
        h0 = h1; h1 = h2; h2 = h3; h3 = h4;
    }
}

__global__ __launch_bounds__(256) void localmean_kernel(const float* __restrict__ in,
                                                        float* __restrict__ out) {
    __shared__ float lds[2][LROWS][W];           // 80 KB -> 2 blocks/CU

    const int b     = (int)blockIdx.x;
    const int plane = b >> 4;                    // 96 planes
    const int strip = b & 15;                    // 16 strips of 32 rows
    const int yA    = strip * 32;
    const int yB    = yA + 16;
    const int t     = threadIdx.x;

    const float* pin  = in  + (size_t)plane * H * W;
    float*       pout = out + (size_t)plane * H * W;

    // Issue BOTH tiles' loads up front: 20 x 16B outstanding per wave.
    stage(pin, &lds[0][0][0], yA, t);
    stage(pin, &lds[1][0][0], yB, t);

    // Tile A ready for this wave once its last 10 issues (tile B) remain.
    asm volatile("s_waitcnt vmcnt(10)" ::: "memory");
    __builtin_amdgcn_s_barrier();                // now ALL waves' A-loads landed
    asm volatile("" ::: "memory");               // no LDS reads hoist above bar
    compute_tile(&lds[0][0][0], pout, yA, t);

    asm volatile("s_waitcnt vmcnt(0)" ::: "memory");
    __builtin_amdgcn_s_barrier();
    asm volatile("" ::: "memory");
    compute_tile(&lds[1][0][0], pout, yB, t);
}

extern "C" void kernel_launch(void* const* d_in, const int* in_sizes, int n_in,
                              void* d_out, int out_size, void* d_ws, size_t ws_size,
                              hipStream_t stream) {
    const float* in = (const float*)d_in[0];
    float* out = (float*)d_out;
    const int planes = in_sizes[0] / (H * W);    // 96
    dim3 grid(planes * 16);                      // 1536 blocks = 3 rounds of 512
    dim3 block(256);
    localmean_kernel<<<grid, block, 0, stream>>>(in, out);
}